// Round 3
// baseline (318.698 us; speedup 1.0000x reference)
//
#include <hip/hip_runtime.h>

// ---------------------------------------------------------------------------
// QGaloreLinear: y = x @ dequant(qw)^T + bias.  M=8192, N=4096, K=4096.
// R3: 256x256-tile 4-phase bf16 MFMA GEMM, 32x32x16 MFMA (2382 TF pipe,
//   half the instruction count of 16x16x32). T1 XCD swizzle, T2 slot-XOR
//   LDS swizzle (both sides), counted vmcnt(6), T5 setprio. Race-free stage
//   placement: A1(kt+1)@p0->nbuf, B0(kt+2)@p2, B1+A0(kt+2)@p3 (regions only
//   overwritten >=1 barrier after their last read).
// ---------------------------------------------------------------------------

typedef __attribute__((ext_vector_type(8)))  short bf16x8;
typedef __attribute__((ext_vector_type(8)))  unsigned short ushort8;
typedef __attribute__((ext_vector_type(16))) float f32x16;

__device__ inline unsigned short f2bf(float f) {
  union { float f; unsigned int u; } v; v.f = f;
  unsigned int u = v.u;
  return (unsigned short)((u + 0x7fffu + ((u >> 16) & 1u)) >> 16);
}

// ---- kernel 1: dequantize int32 qweight -> bf16 Wb[N][K] --------------------
__global__ void dequant_w_kernel(const int* __restrict__ q,
                                 const float* __restrict__ sc,
                                 const float* __restrict__ zp,
                                 ushort8* __restrict__ wb, int total8) {
  int t = blockIdx.x * blockDim.x + threadIdx.x;
  if (t >= total8) return;
  const int4* q4 = (const int4*)q + (size_t)t * 2;
  int4 a = q4[0];
  int4 b = q4[1];
  int g = t >> 5;               // (t*8)/256
  float s = sc[g], z = zp[g];
  ushort8 o;
  o[0] = f2bf(((float)a.x - z) * s);
  o[1] = f2bf(((float)a.y - z) * s);
  o[2] = f2bf(((float)a.z - z) * s);
  o[3] = f2bf(((float)a.w - z) * s);
  o[4] = f2bf(((float)b.x - z) * s);
  o[5] = f2bf(((float)b.y - z) * s);
  o[6] = f2bf(((float)b.z - z) * s);
  o[7] = f2bf(((float)b.w - z) * s);
  wb[t] = o;
}

// ---- kernel 2: convert fp32 x -> bf16 Xb[M][K] ------------------------------
__global__ void convert_x_kernel(const float* __restrict__ x,
                                 ushort8* __restrict__ xb, int total8) {
  int t = blockIdx.x * blockDim.x + threadIdx.x;
  if (t >= total8) return;
  const float4* x4 = (const float4*)x + (size_t)t * 2;
  float4 a = x4[0];
  float4 b = x4[1];
  ushort8 o;
  o[0] = f2bf(a.x); o[1] = f2bf(a.y); o[2] = f2bf(a.z); o[3] = f2bf(a.w);
  o[4] = f2bf(b.x); o[5] = f2bf(b.y); o[6] = f2bf(b.z); o[7] = f2bf(b.w);
  xb[t] = o;
}

// ---- kernel 3: 256x256 4-phase bf16 GEMM, 32x32x16 --------------------------
#define BM 256
#define BN 256
#define BK 64

#define BAR()        asm volatile("s_barrier" ::: "memory")
#define WAIT_LGKM0() asm volatile("s_waitcnt lgkmcnt(0)" ::: "memory")
#define MFMA32(d, x, y) d = __builtin_amdgcn_mfma_f32_32x32x16_bf16(x, y, d, 0, 0, 0)

__device__ inline void gload_lds16(const void* g, void* l) {
  __builtin_amdgcn_global_load_lds(
      (const __attribute__((address_space(1))) unsigned int*)g,
      (__attribute__((address_space(3))) unsigned int*)l, 16, 0, 0);
}

// Stage one 128-row x 64-col bf16 half-tile (16 KiB). Global source slots are
// pre-swizzled (slot ^ (row&7)) so the linear gload_lds dest + swizzled
// ds_read form the same involution (rule #21).
__device__ inline void stage_half(const unsigned short* __restrict__ gsrc,
                                  char* lds_region, int K, int wave, int lane) {
  const int l3  = lane >> 3;
  const int swz = ((lane & 7) ^ l3) * 8;        // swizzled 16B slot, in elems
#pragma unroll
  for (int inst = 0; inst < 2; ++inst) {
    const int row = inst * 64 + wave * 8 + l3;  // 0..127
    gload_lds16(gsrc + (size_t)row * K + swz,
                lds_region + (size_t)(inst * 512 + wave * 64) * 16);
  }
}

__global__ __launch_bounds__(512, 2)
void gemm256_kernel(const unsigned short* __restrict__ A,  // Xb, M x K
                    const unsigned short* __restrict__ B,  // Wb, N x K
                    const float* __restrict__ bias,
                    float* __restrict__ C,
                    int M, int N, int K) {
  extern __shared__ char lds[];   // 2 bufs x (A 32K + B 32K) = 128 KiB
  const int t    = threadIdx.x;
  const int lane = t & 63;
  const int wave = t >> 6;
  const int wm   = wave >> 2;          // 0..1 -> 128 output rows
  const int wn   = wave & 3;           // 0..3 -> 64 output cols
  const int l31  = lane & 31;
  const int hi32 = lane >> 5;          // 0..1
  const int sx   = lane & 7;

  // T1: bijective XCD swizzle (nwg % 8 == 0 here)
  const int nwg = gridDim.x;
  const int cpx = nwg >> 3;
  const int bid = blockIdx.x;
  const int swzb = (bid & 7) * cpx + (bid >> 3);
  const int ntn = N / BN;
  const int bm = swzb / ntn, bn = swzb % ntn;
  const int row0 = bm * BM, col0 = bn * BN;

  const int NT = K / BK;

  const unsigned short* Asrc = A + (size_t)row0 * K;
  const unsigned short* Bsrc = B + (size_t)col0 * K;

#define STAGE_B0(buf, kt) stage_half(Bsrc + (size_t)(kt) * BK,           (buf) + 32768, K, wave, lane)
#define STAGE_B1(buf, kt) stage_half(Bsrc + (size_t)128 * K + (kt) * BK, (buf) + 49152, K, wave, lane)
#define STAGE_A0(buf, kt) stage_half(Asrc + (size_t)(kt) * BK,           (buf),         K, wave, lane)
#define STAGE_A1(buf, kt) stage_half(Asrc + (size_t)128 * K + (kt) * BK, (buf) + 16384, K, wave, lane)

  // per-thread constant byte offsets
  const int aReg = wm * 16384;                        // A half by wm
  const int bReg = 32768 + (wn >> 1) * 16384;         // B half by wn
  const int aRow0 = (0 * 32 + l31) * 128;             // f=0 row base (A)
  const int aRow1 = (1 * 32 + l31) * 128;             // f=1
  const int aRow2 = (2 * 32 + l31) * 128;             // f=2
  const int aRow3 = (3 * 32 + l31) * 128;             // f=3
  const int bRow0 = ((wn & 1) * 64 + 0 * 32 + l31) * 128;  // g=0
  const int bRow1 = ((wn & 1) * 64 + 1 * 32 + l31) * 128;  // g=1
  // swizzled k-slot byte offsets: slot_raw = ks*2 + hi32, slot = raw ^ sx
#define SOFF(ks) ((((ks) * 2 + hi32) ^ sx) * 16)

  f32x16 acc[4][2] = {};          // [row-frag f][col-frag g]
  bf16x8 a[2][4];                 // 2 live row-frags x 4 k-steps (reused)
  bf16x8 b[2][4];                 // 2 col-frags x 4 k-steps

  // ---- prologue: kt0 full + kt1 {B0,B1,A0} ----
  char* buf0 = lds;
  char* buf1 = lds + 65536;
  STAGE_B0(buf0, 0); STAGE_B1(buf0, 0); STAGE_A0(buf0, 0); STAGE_A1(buf0, 0);
  STAGE_B0(buf1, 1); STAGE_B1(buf1, 1); STAGE_A0(buf1, 1);
  asm volatile("s_waitcnt vmcnt(6)" ::: "memory");
  BAR();

  for (int kt = 0; kt < NT; ++kt) {
    char* buf  = lds + ((size_t)(kt & 1) << 16);
    char* nbuf = lds + ((size_t)((kt & 1) ^ 1) << 16);
    const char* Ab = buf + aReg;
    const char* Bb = buf + bReg;

    // ===== phase 0: read a(f0,f1) 8x + b(g0) 4x ; stage A1(kt+1)->nbuf =====
#pragma unroll
    for (int ks = 0; ks < 4; ++ks) {
      a[0][ks] = *(const bf16x8*)(Ab + aRow0 + SOFF(ks));
      a[1][ks] = *(const bf16x8*)(Ab + aRow1 + SOFF(ks));
      b[0][ks] = *(const bf16x8*)(Bb + bRow0 + SOFF(ks));
    }
    if (kt + 1 < NT) STAGE_A1(nbuf, kt + 1);
    asm volatile("s_waitcnt lgkmcnt(8)" ::: "memory");
    BAR();
    WAIT_LGKM0();
    __builtin_amdgcn_s_setprio(1);
#pragma unroll
    for (int ks = 0; ks < 4; ++ks) {
      MFMA32(acc[0][0], a[0][ks], b[0][ks]);
      MFMA32(acc[1][0], a[1][ks], b[0][ks]);
    }
    __builtin_amdgcn_s_setprio(0);
    BAR();

    // ===== phase 1: read b(g1) 4x ; no stage =====
#pragma unroll
    for (int ks = 0; ks < 4; ++ks)
      b[1][ks] = *(const bf16x8*)(Bb + bRow1 + SOFF(ks));
    BAR();
    WAIT_LGKM0();
    __builtin_amdgcn_s_setprio(1);
#pragma unroll
    for (int ks = 0; ks < 4; ++ks) {
      MFMA32(acc[0][1], a[0][ks], b[1][ks]);
      MFMA32(acc[1][1], a[1][ks], b[1][ks]);
    }
    __builtin_amdgcn_s_setprio(0);
    BAR();

    // ===== phase 2: read a(f2,f3) 8x (reuse regs) ; stage B0(kt+2)->buf =====
#pragma unroll
    for (int ks = 0; ks < 4; ++ks) {
      a[0][ks] = *(const bf16x8*)(Ab + aRow2 + SOFF(ks));
      a[1][ks] = *(const bf16x8*)(Ab + aRow3 + SOFF(ks));
    }
    if (kt + 2 < NT) STAGE_B0(buf, kt + 2);
    BAR();
    WAIT_LGKM0();
    __builtin_amdgcn_s_setprio(1);
#pragma unroll
    for (int ks = 0; ks < 4; ++ks) {
      MFMA32(acc[2][0], a[0][ks], b[0][ks]);
      MFMA32(acc[3][0], a[1][ks], b[0][ks]);
    }
    __builtin_amdgcn_s_setprio(0);
    BAR();

    // ===== phase 3: no reads ; stage B1,A0(kt+2)->buf ; counted vmcnt =====
    if (kt + 2 < NT) { STAGE_B1(buf, kt + 2); STAGE_A0(buf, kt + 2); }
    BAR();
    __builtin_amdgcn_s_setprio(1);
#pragma unroll
    for (int ks = 0; ks < 4; ++ks) {
      MFMA32(acc[2][1], a[0][ks], b[1][ks]);
      MFMA32(acc[3][1], a[1][ks], b[1][ks]);
    }
    __builtin_amdgcn_s_setprio(0);
    if (kt + 2 < NT)      asm volatile("s_waitcnt vmcnt(6)" ::: "memory");
    else if (kt + 1 < NT) asm volatile("s_waitcnt vmcnt(0)" ::: "memory");
    BAR();
  }

  // ---- epilogue: C = acc + bias ----
  // 32x32 C/D layout: col = lane&31, row = (reg&3) + 8*(reg>>2) + 4*(lane>>5)
#pragma unroll
  for (int g = 0; g < 2; ++g) {
    const int col = col0 + wn * 64 + g * 32 + l31;
    const float bv = bias[col];
#pragma unroll
    for (int f = 0; f < 4; ++f) {
      const int rbase = row0 + wm * 128 + f * 32 + 4 * hi32;
#pragma unroll
      for (int q = 0; q < 4; ++q)
#pragma unroll
        for (int j = 0; j < 4; ++j)
          C[(size_t)(rbase + 8 * q + j) * N + col] = acc[f][g][q * 4 + j] + bv;
    }
  }
#undef STAGE_B0
#undef STAGE_B1
#undef STAGE_A0
#undef STAGE_A1
#undef SOFF
}

// ---------------------------------------------------------------------------
extern "C" void kernel_launch(void* const* d_in, const int* in_sizes, int n_in,
                              void* d_out, int out_size, void* d_ws, size_t ws_size,
                              hipStream_t stream) {
  const float* x      = (const float*)d_in[0];
  const int*   qw     = (const int*)d_in[1];
  const float* scales = (const float*)d_in[2];
  const float* zeros  = (const float*)d_in[3];
  const float* bias   = (const float*)d_in[4];
  float* out = (float*)d_out;

  const int OUT = in_sizes[4];                 // 4096
  const int IN  = in_sizes[1] / OUT;           // 4096
  const int M   = in_sizes[0] / IN;            // 8192

  unsigned short* wb = (unsigned short*)d_ws;                 // OUT*IN bf16
  unsigned short* xb = wb + (size_t)OUT * IN;                 // M*IN  bf16

  {
    int total8 = OUT * IN / 8;
    dequant_w_kernel<<<(total8 + 255) / 256, 256, 0, stream>>>(
        qw, scales, zeros, (ushort8*)wb, total8);
  }
  {
    int total8 = (int)((size_t)M * IN / 8);
    convert_x_kernel<<<(total8 + 255) / 256, 256, 0, stream>>>(
        x, (ushort8*)xb, total8);
  }
  {
    hipFuncSetAttribute((const void*)gemm256_kernel,
                        hipFuncAttributeMaxDynamicSharedMemorySize, 131072);
    dim3 grid((M / BM) * (OUT / BN));
    gemm256_kernel<<<grid, 512, 131072, stream>>>(xb, wb, bias, out, M, OUT, IN);
  }
}

// Round 4
// 278.964 us; speedup vs baseline: 1.1424x; 1.1424x over previous
//
#include <hip/hip_runtime.h>

// ---------------------------------------------------------------------------
// QGaloreLinear: y = x @ dequant(qw)^T + bias.  M=8192, N=4096, K=4096.
// R4: 256x256 tile, 16x16x32 MFMA (R2's proven conflict-free LDS pattern),
//   ONE barrier per phase, register reads issued one phase ahead so ds_read
//   (LDS pipe) overlaps MFMA (matrix pipe). Counted vmcnt(4) once per K-tile.
//   Phase = { BAR; setprio1; 16 MFMA; setprio0; stage; reads-for-next }.
//   Quadrants (m0n0)(m0n1)(m1n0)(m1n1); a[4][2]/b[4][2] single-buffered.
// ---------------------------------------------------------------------------

typedef __attribute__((ext_vector_type(8))) short bf16x8;
typedef __attribute__((ext_vector_type(8))) unsigned short ushort8;
typedef __attribute__((ext_vector_type(4))) float f32x4;

__device__ inline unsigned short f2bf(float f) {
  union { float f; unsigned int u; } v; v.f = f;
  unsigned int u = v.u;
  return (unsigned short)((u + 0x7fffu + ((u >> 16) & 1u)) >> 16);
}

// ---- kernel 1: dequantize int32 qweight -> bf16 Wb[N][K] --------------------
__global__ void dequant_w_kernel(const int* __restrict__ q,
                                 const float* __restrict__ sc,
                                 const float* __restrict__ zp,
                                 ushort8* __restrict__ wb, int total8) {
  int t = blockIdx.x * blockDim.x + threadIdx.x;
  if (t >= total8) return;
  const int4* q4 = (const int4*)q + (size_t)t * 2;
  int4 a = q4[0];
  int4 b = q4[1];
  int g = t >> 5;
  float s = sc[g], z = zp[g];
  ushort8 o;
  o[0] = f2bf(((float)a.x - z) * s);
  o[1] = f2bf(((float)a.y - z) * s);
  o[2] = f2bf(((float)a.z - z) * s);
  o[3] = f2bf(((float)a.w - z) * s);
  o[4] = f2bf(((float)b.x - z) * s);
  o[5] = f2bf(((float)b.y - z) * s);
  o[6] = f2bf(((float)b.z - z) * s);
  o[7] = f2bf(((float)b.w - z) * s);
  wb[t] = o;
}

// ---- kernel 2: convert fp32 x -> bf16 Xb[M][K] ------------------------------
__global__ void convert_x_kernel(const float* __restrict__ x,
                                 ushort8* __restrict__ xb, int total8) {
  int t = blockIdx.x * blockDim.x + threadIdx.x;
  if (t >= total8) return;
  const float4* x4 = (const float4*)x + (size_t)t * 2;
  float4 a = x4[0];
  float4 b = x4[1];
  ushort8 o;
  o[0] = f2bf(a.x); o[1] = f2bf(a.y); o[2] = f2bf(a.z); o[3] = f2bf(a.w);
  o[4] = f2bf(b.x); o[5] = f2bf(b.y); o[6] = f2bf(b.z); o[7] = f2bf(b.w);
  xb[t] = o;
}

// ---- kernel 3: 256x256 single-barrier-phase bf16 GEMM -----------------------
#define BM 256
#define BN 256
#define BK 64

#define BAR() asm volatile("s_barrier" ::: "memory")
#define MFMA16(d, x, y) d = __builtin_amdgcn_mfma_f32_16x16x32_bf16(x, y, d, 0, 0, 0)

__device__ inline void gload_lds16(const void* g, void* l) {
  __builtin_amdgcn_global_load_lds(
      (const __attribute__((address_space(1))) unsigned int*)g,
      (__attribute__((address_space(3))) unsigned int*)l, 16, 0, 0);
}

// Stage one 128-row x 64-col bf16 half-tile (16 KiB). Global 16B-slot is
// pre-swizzled (slot ^ (row&7)); LDS dest linear (rule #21 both-sides).
__device__ inline void stage_half(const unsigned short* __restrict__ gsrc,
                                  char* lds_region, int K, int wave, int lane) {
  const int l3  = lane >> 3;
  const int swz = ((lane & 7) ^ l3) * 8;        // swizzled 16B slot, in elems
#pragma unroll
  for (int inst = 0; inst < 2; ++inst) {
    const int row = inst * 64 + wave * 8 + l3;  // 0..127
    gload_lds16(gsrc + (size_t)row * K + swz,
                lds_region + (size_t)(inst * 512 + wave * 64) * 16);
  }
}

__global__ __launch_bounds__(512, 2)
void gemm256_kernel(const unsigned short* __restrict__ A,  // Xb, M x K
                    const unsigned short* __restrict__ B,  // Wb, N x K
                    const float* __restrict__ bias,
                    float* __restrict__ C,
                    int M, int N, int K) {
  extern __shared__ char lds[];   // buf: A0@0 A1@16K B0@32K B1@48K; dbuf @64K
  const int t    = threadIdx.x;
  const int lane = t & 63;
  const int wave = t >> 6;
  const int wm   = wave >> 2;          // 0..1 -> 128 rows
  const int wn   = wave & 3;           // 0..3 -> 64 cols
  const int lr   = lane & 15;
  const int hi   = lane >> 4;          // 0..3
  const int l7   = lane & 7;

  // T1: bijective XCD swizzle (nwg % 8 == 0)
  const int nwg = gridDim.x;
  const int cpx = nwg >> 3;
  const int bid = blockIdx.x;
  const int swzb = (bid & 7) * cpx + (bid >> 3);
  const int ntn = N / BN;
  const int bm = swzb / ntn, bn = swzb % ntn;
  const int row0 = bm * BM, col0 = bn * BN;

  const int NT = K / BK;

  // conflict-free (measured R2) swizzled ds_read offsets, kk=0 / kk=32
  const int soff0 = ((hi) ^ l7) * 16;
  const int soff1 = ((4 + hi) ^ l7) * 16;

  const unsigned short* Asrc = A + (size_t)row0 * K;
  const unsigned short* Bsrc = B + (size_t)col0 * K;

#define STAGE_A0(buf, kt) stage_half(Asrc + (size_t)(kt) * BK,           (buf),         K, wave, lane)
#define STAGE_A1(buf, kt) stage_half(Asrc + (size_t)128 * K + (kt) * BK, (buf) + 16384, K, wave, lane)
#define STAGE_B0(buf, kt) stage_half(Bsrc + (size_t)(kt) * BK,           (buf) + 32768, K, wave, lane)
#define STAGE_B1(buf, kt) stage_half(Bsrc + (size_t)128 * K + (kt) * BK, (buf) + 49152, K, wave, lane)

  f32x4 acc[8][4] = {};
  bf16x8 a[4][2];   // current m-half, 4 frags x 2 ks
  bf16x8 b[4][2];   // all 4 n-frags of this kt

  // reads: A-half mh from buf: base = buf + wm*16384 + mh*8192
#define READ_A(mh, bufp) {                                                    \
    const char* Ab_ = (const char*)(bufp) + wm * 16384 + (mh) * 8192;         \
    _Pragma("unroll")                                                         \
    for (int mm = 0; mm < 4; ++mm) {                                          \
      const int r_ = (mm * 16 + lr) * 128;                                    \
      a[mm][0] = *(const bf16x8*)(Ab_ + r_ + soff0);                          \
      a[mm][1] = *(const bf16x8*)(Ab_ + r_ + soff1);                          \
    } }
#define READ_B(nh, bufp) {                                                    \
    const char* Bb_ = (const char*)(bufp) + 32768 + wn * 8192;                \
    _Pragma("unroll")                                                         \
    for (int nn = 0; nn < 2; ++nn) {                                          \
      const int r_ = (((nh) * 2 + nn) * 16 + lr) * 128;                       \
      b[(nh) * 2 + nn][0] = *(const bf16x8*)(Bb_ + r_ + soff0);               \
      b[(nh) * 2 + nn][1] = *(const bf16x8*)(Bb_ + r_ + soff1);               \
    } }
#define MFMA_QUAD(mh, nh)                                                     \
    __builtin_amdgcn_s_setprio(1);                                            \
    _Pragma("unroll")                                                         \
    for (int mm = 0; mm < 4; ++mm)                                            \
      _Pragma("unroll")                                                       \
      for (int nn = 0; nn < 2; ++nn) {                                        \
        MFMA16(acc[(mh) * 4 + mm][(nh) * 2 + nn], a[mm][0], b[(nh) * 2 + nn][0]); \
        MFMA16(acc[(mh) * 4 + mm][(nh) * 2 + nn], a[mm][1], b[(nh) * 2 + nn][1]); \
      }                                                                       \
    __builtin_amdgcn_s_setprio(0);

  // ---- prologue: stage buf0 fully + buf1 {A0,B0,B1}; A1(1) comes @q0(0) ----
  char* buf0 = lds;
  char* buf1 = lds + 65536;
  STAGE_A0(buf0, 0); STAGE_A1(buf0, 0); STAGE_B0(buf0, 0); STAGE_B1(buf0, 0);
  STAGE_A0(buf1, 1); STAGE_B0(buf1, 1); STAGE_B1(buf1, 1);
  asm volatile("s_waitcnt vmcnt(6)" ::: "memory");
  BAR();
  READ_A(0, buf0);
  READ_B(0, buf0);

  for (int kt = 0; kt < NT; ++kt) {
    char* buf  = lds + ((size_t)(kt & 1) << 16);
    char* nbuf = lds + ((size_t)((kt & 1) ^ 1) << 16);

    // ===== q0: MFMA(m0,n0) ; stage A1(kt+1)->nbuf ; read b(n1) =====
    BAR();
    MFMA_QUAD(0, 0);
    if (kt + 1 < NT) STAGE_A1(nbuf, kt + 1);
    READ_B(1, buf);

    // ===== q1: MFMA(m0,n1) ; stage B0(kt+2)->buf ; read a(m1) =====
    BAR();
    MFMA_QUAD(0, 1);
    if (kt + 2 < NT) STAGE_B0(buf, kt + 2);
    READ_A(1, buf);

    // ===== q2: MFMA(m1,n0) ; stage B1(kt+2)->buf ; vmcnt =====
    BAR();
    MFMA_QUAD(1, 0);
    if (kt + 2 < NT) {
      STAGE_B1(buf, kt + 2);
      asm volatile("s_waitcnt vmcnt(4)" ::: "memory");
    } else {
      asm volatile("s_waitcnt vmcnt(0)" ::: "memory");
    }

    // ===== q3: MFMA(m1,n1) ; stage A0(kt+2)->buf ; read next-kt a(m0),b(n0) =====
    BAR();
    MFMA_QUAD(1, 1);
    if (kt + 2 < NT) STAGE_A0(buf, kt + 2);
    if (kt + 1 < NT) {
      READ_A(0, nbuf);
      READ_B(0, nbuf);
    }
  }

  // ---- epilogue: C = acc + bias ----
#pragma unroll
  for (int n = 0; n < 4; ++n) {
    const int col = col0 + wn * 64 + n * 16 + lr;
    const float bv = bias[col];
#pragma unroll
    for (int m = 0; m < 8; ++m) {
      const int rbase = row0 + wm * 128 + m * 16 + hi * 4;
#pragma unroll
      for (int j = 0; j < 4; ++j)
        C[(size_t)(rbase + j) * N + col] = acc[m][n][j] + bv;
    }
  }
#undef STAGE_A0
#undef STAGE_A1
#undef STAGE_B0
#undef STAGE_B1
#undef READ_A
#undef READ_B
#undef MFMA_QUAD
}

// ---------------------------------------------------------------------------
extern "C" void kernel_launch(void* const* d_in, const int* in_sizes, int n_in,
                              void* d_out, int out_size, void* d_ws, size_t ws_size,
                              hipStream_t stream) {
  const float* x      = (const float*)d_in[0];
  const int*   qw     = (const int*)d_in[1];
  const float* scales = (const float*)d_in[2];
  const float* zeros  = (const float*)d_in[3];
  const float* bias   = (const float*)d_in[4];
  float* out = (float*)d_out;

  const int OUT = in_sizes[4];                 // 4096
  const int IN  = in_sizes[1] / OUT;           // 4096
  const int M   = in_sizes[0] / IN;            // 8192

  unsigned short* wb = (unsigned short*)d_ws;                 // OUT*IN bf16
  unsigned short* xb = wb + (size_t)OUT * IN;                 // M*IN  bf16

  {
    int total8 = OUT * IN / 8;
    dequant_w_kernel<<<(total8 + 255) / 256, 256, 0, stream>>>(
        qw, scales, zeros, (ushort8*)wb, total8);
  }
  {
    int total8 = (int)((size_t)M * IN / 8);
    convert_x_kernel<<<(total8 + 255) / 256, 256, 0, stream>>>(
        x, (ushort8*)xb, total8);
  }
  {
    hipFuncSetAttribute((const void*)gemm256_kernel,
                        hipFuncAttributeMaxDynamicSharedMemorySize, 131072);
    dim3 grid((M / BM) * (OUT / BN));
    gemm256_kernel<<<grid, 512, 131072, stream>>>(xb, wb, bias, out, M, OUT, IN);
  }
}